// Round 11
// baseline (404.582 us; speedup 1.0000x reference)
//
#include <hip/hip_runtime.h>

#define BB 4
#define SS 2048
#define HH 4
#define DD 192
#define QT 16
#define NT (SS / 2 / 64)
#define NEG_BIG (-1e9f)
#define MB_NEG 0xCE6Eu   // bf16(-1e9) approx

typedef __attribute__((ext_vector_type(8))) short short8;
typedef __attribute__((ext_vector_type(4))) float f32x4;

__device__ inline ushort f2bf(float x) {
    union { float f; unsigned u; } v; v.f = x;
    unsigned r = (v.u + 0x7FFFu + ((v.u >> 16) & 1u)) >> 16;
    return (ushort)r;
}
__device__ inline float bf2f(ushort x) {
    union { unsigned u; float f; } v; v.u = ((unsigned)x) << 16;
    return v.f;
}
// wave-local fence: all prior ds ops complete/visible within this wave
__device__ inline void wave_lds_fence() {
    __builtin_amdgcn_wave_barrier();
    __builtin_amdgcn_s_waitcnt(0xC07F);   // vmcnt(63) expcnt(7) lgkmcnt(0)
    __builtin_amdgcn_wave_barrier();
}

// ---------------------------------------------------------------------------
// Transpose the four weight matrices: WT[c][j] = W[j][c].  grid (6,6,4).
// ---------------------------------------------------------------------------
__global__ __launch_bounds__(256) void wt_kernel(
    const float* __restrict__ Wq, const float* __restrict__ Wk,
    const float* __restrict__ Wv, const float* __restrict__ Wo,
    float* __restrict__ WTall)
{
    __shared__ float tile[32][33];
    const float* W = (blockIdx.z == 0) ? Wq : (blockIdx.z == 1) ? Wk
                   : (blockIdx.z == 2) ? Wv : Wo;
    float* WT = WTall + (size_t)blockIdx.z * DD * DD;
    const int c0 = blockIdx.x * 32, j0 = blockIdx.y * 32;
    const int tx = threadIdx.x & 31, ty = threadIdx.x >> 5;
#pragma unroll
    for (int k = 0; k < 4; ++k)
        tile[ty + 8 * k][tx] = W[(size_t)(j0 + ty + 8 * k) * DD + c0 + tx];
    __syncthreads();
#pragma unroll
    for (int k = 0; k < 4; ++k)
        WT[(size_t)(c0 + ty + 8 * k) * DD + j0 + tx] = tile[tx][ty + 8 * k];
}

// ---------------------------------------------------------------------------
// Fused QKV projection via WT (coalesced). 192 thr, 16 rows/block, grid(512,3).
// unroll 4 (was 2): 16 WT/xs loads in flight per thread.
// ---------------------------------------------------------------------------
__global__ __launch_bounds__(192) void qkv_proj_kernel(
    const float* __restrict__ Xq, const float* __restrict__ Xk,
    const float* __restrict__ Xv, const float* __restrict__ WTall,
    ushort* __restrict__ qpad, ushort* __restrict__ kpad,
    ushort* __restrict__ vT)
{
    const int mode = blockIdx.y;
    const float* __restrict__ X = (mode == 0) ? Xq : (mode == 1) ? Xk : Xv;
    const float* __restrict__ WT = WTall + (size_t)mode * DD * DD;

    __shared__ __align__(16) float xs[16][DD];   // 12 KB
    const int row0 = blockIdx.x * 16;
    const int t = threadIdx.x;
    {
        const float4* src = (const float4*)(X + (size_t)row0 * DD);
        float4* dst = (float4*)&xs[0][0];
        for (int i = t; i < 16 * DD / 4; i += 192) dst[i] = src[i];
    }
    __syncthreads();

    const int jt = (t % 48) * 4;
    const int rowg = t / 48;           // 0..3, rows rowg*4 .. rowg*4+3

    float acc[4][4];
#pragma unroll
    for (int r = 0; r < 4; ++r)
#pragma unroll
        for (int j = 0; j < 4; ++j) acc[r][j] = 0.f;

#pragma unroll 4
    for (int k4 = 0; k4 < DD / 4; ++k4) {
        float4 w0 = *(const float4*)&WT[(size_t)(k4 * 4 + 0) * DD + jt];
        float4 w1 = *(const float4*)&WT[(size_t)(k4 * 4 + 1) * DD + jt];
        float4 w2 = *(const float4*)&WT[(size_t)(k4 * 4 + 2) * DD + jt];
        float4 w3 = *(const float4*)&WT[(size_t)(k4 * 4 + 3) * DD + jt];
#pragma unroll
        for (int r = 0; r < 4; ++r) {
            float4 xv = *(const float4*)&xs[rowg * 4 + r][k4 * 4];
            acc[r][0] = fmaf(xv.x, w0.x, acc[r][0]); acc[r][1] = fmaf(xv.x, w0.y, acc[r][1]);
            acc[r][2] = fmaf(xv.x, w0.z, acc[r][2]); acc[r][3] = fmaf(xv.x, w0.w, acc[r][3]);
            acc[r][0] = fmaf(xv.y, w1.x, acc[r][0]); acc[r][1] = fmaf(xv.y, w1.y, acc[r][1]);
            acc[r][2] = fmaf(xv.y, w1.z, acc[r][2]); acc[r][3] = fmaf(xv.y, w1.w, acc[r][3]);
            acc[r][0] = fmaf(xv.z, w2.x, acc[r][0]); acc[r][1] = fmaf(xv.z, w2.y, acc[r][1]);
            acc[r][2] = fmaf(xv.z, w2.z, acc[r][2]); acc[r][3] = fmaf(xv.z, w2.w, acc[r][3]);
            acc[r][0] = fmaf(xv.w, w3.x, acc[r][0]); acc[r][1] = fmaf(xv.w, w3.y, acc[r][1]);
            acc[r][2] = fmaf(xv.w, w3.z, acc[r][2]); acc[r][3] = fmaf(xv.w, w3.w, acc[r][3]);
        }
    }

    if (mode < 2) {
        ushort* __restrict__ out = (mode == 0) ? qpad : kpad;
        const int hd = jt / 48, f = jt % 48;
#pragma unroll
        for (int r = 0; r < 4; ++r) {
            ushort4 o;
            o.x = f2bf(acc[r][0]); o.y = f2bf(acc[r][1]);
            o.z = f2bf(acc[r][2]); o.w = f2bf(acc[r][3]);
            *(ushort4*)&out[((size_t)(row0 + rowg * 4 + r) * HH + hd) * 64 + f] = o;
        }
        // zero pad f=48..63 for all 16 rows x 4 heads (2 int4 each)
        const int4 z = make_int4(0, 0, 0, 0);
        for (int i = t; i < 128; i += 192) {
            const int row = i >> 3, hh = (i >> 1) & 3, half = i & 1;
            *(int4*)&out[((size_t)(row0 + row) * HH + hh) * 64 + 48 + half * 8] = z;
        }
    } else {
        const int b = row0 >> 11, s0 = row0 & (SS - 1);
#pragma unroll
        for (int j = 0; j < 4; ++j) {
            const int col = jt + j, hd = col / 48, f = col % 48;
#pragma unroll
            for (int p = 0; p < 2; ++p) {
                unsigned pk = (unsigned)f2bf(acc[2 * p][j]) |
                              ((unsigned)f2bf(acc[2 * p + 1][j]) << 16);
                *(unsigned*)&vT[(((size_t)b * HH + hd) * 48 + f) * SS +
                                s0 + rowg * 4 + 2 * p] = pk;
            }
        }
    }
}

// ---------------------------------------------------------------------------
// MFMA attention, SINGLE PASS (R9/R10, stable ~154-167 us).  Unchanged.
// ---------------------------------------------------------------------------
__device__ inline f32x4 qk_tile(const ushort* kp, short8 qa0, short8 qa1) {
    short8 kb0 = *(const short8*)(kp);
    short8 kb1 = *(const short8*)(kp + 32);
    f32x4 d = {0.f, 0.f, 0.f, 0.f};
    d = __builtin_amdgcn_mfma_f32_16x16x32_bf16(qa0, kb0, d, 0, 0, 0);
    d = __builtin_amdgcn_mfma_f32_16x16x32_bf16(qa1, kb1, d, 0, 0, 0);
    return d;
}

__global__ __launch_bounds__(512, 4) void attn_kernel(
    const ushort* __restrict__ qpad, const ushort* __restrict__ kpad,
    const ushort* __restrict__ vT, const int* __restrict__ mask,
    const float* __restrict__ bias,
    ushort* __restrict__ wscr, float* __restrict__ linv_g,
    float* __restrict__ oattn)
{
    __shared__ __align__(16) ushort wb[2][8][QT][72];  // 36864 B double-buffered
    __shared__ float l_scr[8][QT];                     // 512 B

    const int b  = blockIdx.x >> 7;
    const int q0 = (blockIdx.x & 127) * QT;
    const int t = threadIdx.x;
    const int w = t >> 6;
    const int h = w & 3;
    const int kh = w >> 2;
    const int lane = t & 63;
    const int n16 = lane & 15, quad = lane >> 4;
    const int kbase0 = kh * (SS / 2);

    const ushort* qbase =
        qpad + ((size_t)(b * SS + q0 + n16) * HH + h) * 64 + quad * 8;
    const short8 qa0 = *(const short8*)(qbase);
    const short8 qa1 = *(const short8*)(qbase + 32);
    const ushort* kbase = kpad + (size_t)b * SS * HH * 64 + h * 64 + quad * 8;

    const int srow = lane >> 4;          // staging row base (+4*rr)
    const int skey = (lane & 15) * 4;    // staging key (float4/int4)
    const int* mrow0 = mask + (size_t)(b * SS + q0) * SS + kbase0 + skey;
    const float* brow0 = bias + (size_t)(h * SS + q0) * SS + kbase0 + skey;

    float l_[4] = {0.f, 0.f, 0.f, 0.f};
    f32x4 pv[3];
#pragma unroll
    for (int nb = 0; nb < 3; ++nb) pv[nb] = (f32x4){0.f, 0.f, 0.f, 0.f};

    // ---- prologue: load kt0, stage into wb[0], load kt1 into regs ----
    int4  mzc[4];
    float4 bvc[4];
#pragma unroll
    for (int rr = 0; rr < 4; ++rr) {
        const int row = rr * 4 + srow;
        mzc[rr] = *(const int4*)(mrow0 + (size_t)row * SS);
        bvc[rr] = *(const float4*)(brow0 + (size_t)row * SS);
    }
#pragma unroll
    for (int rr = 0; rr < 4; ++rr) {
        const int row = rr * 4 + srow;
        ushort4 o;
        o.x = mzc[rr].x ? f2bf(bvc[rr].x) : (ushort)MB_NEG;
        o.y = mzc[rr].y ? f2bf(bvc[rr].y) : (ushort)MB_NEG;
        o.z = mzc[rr].z ? f2bf(bvc[rr].z) : (ushort)MB_NEG;
        o.w = mzc[rr].w ? f2bf(bvc[rr].w) : (ushort)MB_NEG;
        *(ushort4*)&wb[0][w][row][skey] = o;
    }
#pragma unroll
    for (int rr = 0; rr < 4; ++rr) {
        const int row = rr * 4 + srow;
        mzc[rr] = *(const int4*)(mrow0 + (size_t)row * SS + 64);
        bvc[rr] = *(const float4*)(brow0 + (size_t)row * SS + 64);
    }
    wave_lds_fence();   // stage(0) visible

    int buf = 0;
    for (int kt = 0; kt < NT; ++kt) {
        const int kb = kt * 64;

        // ---- QK + exp; w overwrites its own mb slot in wb[buf] ----
#pragma unroll
        for (int g = 0; g < 4; ++g) {
            const int key = kbase0 + kb + g * 16 + n16;
            f32x4 d = qk_tile(kbase + (size_t)key * (HH * 64), qa0, qa1);
#pragma unroll
            for (int r = 0; r < 4; ++r) {
                float wgt = __expf(d[r] + bf2f(wb[buf][w][quad * 4 + r][g * 16 + n16]));
                l_[r] += wgt;
                wb[buf][w][quad * 4 + r][g * 16 + n16] = f2bf(wgt);
            }
        }

        wave_lds_fence();   // FENCE1: w visible; stream(kt-1) reads drained

        // ---- stage kt+1 into wb[buf^1] (drains under PV below) ----
        if (kt + 1 < NT) {
#pragma unroll
            for (int rr = 0; rr < 4; ++rr) {
                const int row = rr * 4 + srow;
                ushort4 o;
                o.x = mzc[rr].x ? f2bf(bvc[rr].x) : (ushort)MB_NEG;
                o.y = mzc[rr].y ? f2bf(bvc[rr].y) : (ushort)MB_NEG;
                o.z = mzc[rr].z ? f2bf(bvc[rr].z) : (ushort)MB_NEG;
                o.w = mzc[rr].w ? f2bf(bvc[rr].w) : (ushort)MB_NEG;
                *(ushort4*)&wb[buf ^ 1][w][row][skey] = o;
            }
        }
        // ---- prefetch kt+2 into regs ----
        if (kt + 2 < NT) {
#pragma unroll
            for (int rr = 0; rr < 4; ++rr) {
                const int row = rr * 4 + srow;
                mzc[rr] = *(const int4*)(mrow0 + (size_t)row * SS + kb + 128);
                bvc[rr] = *(const float4*)(brow0 + (size_t)row * SS + kb + 128);
            }
        }

        // ---- PV with unnormalized w ----
        const short8 wa0 = *(const short8*)&wb[buf][w][n16][quad * 8];
        const short8 wa1 = *(const short8*)&wb[buf][w][n16][32 + quad * 8];
#pragma unroll
        for (int nb = 0; nb < 3; ++nb) {
            const ushort* vb = vT + ((size_t)(b * HH + h) * 48 + nb * 16 + n16) * SS
                               + kbase0 + kb + quad * 8;
            short8 v0 = *(const short8*)(vb);
            short8 v1 = *(const short8*)(vb + 32);
            pv[nb] = __builtin_amdgcn_mfma_f32_16x16x32_bf16(wa0, v0, pv[nb], 0, 0, 0);
            pv[nb] = __builtin_amdgcn_mfma_f32_16x16x32_bf16(wa1, v1, pv[nb], 0, 0, 0);
        }

        // ---- stream unnormalized w tile to wscr (b,q,h,k layout) ----
        {
            const int r4 = lane >> 4;
            const int k4 = (lane & 15) * 4;
#pragma unroll
            for (int it = 0; it < 4; ++it) {
                const int row = it * 4 + r4;
                ushort4 wv = *(const ushort4*)&wb[buf][w][row][k4];
                *(ushort4*)&wscr[((size_t)(b * SS + q0 + row) * HH + h) * SS +
                                 kbase0 + kb + k4] = wv;
            }
        }

        wave_lds_fence();   // FENCE2: stage(kt+1) visible before next QK
        buf ^= 1;
    }

    // ---- reduce l across the 16 key-lanes ----
#pragma unroll
    for (int r = 0; r < 4; ++r) {
        float ll = l_[r];
#pragma unroll
        for (int off = 1; off < 16; off <<= 1) ll += __shfl_xor(ll, off);
        l_[r] = ll;
    }
    if (n16 == 0) {
#pragma unroll
        for (int r = 0; r < 4; ++r) l_scr[w][quad * 4 + r] = l_[r];
    }

    // ALL waves must be done with wb before scr (aliasing wb) is written.
    __syncthreads();

    // kh==1 stashes raw pv into LDS scratch (aliases wb)
    float* scr = (float*)&wb[0][0][0][0];
    if (kh == 1) {
#pragma unroll
        for (int nb = 0; nb < 3; ++nb)
            *(f32x4*)&scr[((size_t)(h * 64 + lane)) * 12 + nb * 4] = pv[nb];
    }
    __syncthreads();

    if (kh == 0) {
        float linv[4];
#pragma unroll
        for (int r = 0; r < 4; ++r)
            linv[r] = 1.0f / (l_scr[h][quad * 4 + r] + l_scr[h + 4][quad * 4 + r]);
        if (n16 == 0) {
#pragma unroll
            for (int r = 0; r < 4; ++r)
                linv_g[((size_t)b * HH + h) * SS + q0 + quad * 4 + r] = linv[r];
        }
#pragma unroll
        for (int nb = 0; nb < 3; ++nb) {
            f32x4 po = *(const f32x4*)&scr[((size_t)(h * 64 + lane)) * 12 + nb * 4];
#pragma unroll
            for (int r = 0; r < 4; ++r)
                oattn[((size_t)(b * SS + q0 + quad * 4 + r)) * DD +
                      h * 48 + nb * 16 + n16] = (pv[nb][r] + po[r]) * linv[r];
        }
    }
}

// ---------------------------------------------------------------------------
// Fused tail: o_proj (blocks [0,512)) + out1 (blocks [512, 512+2048)).
// out1 role handles FOUR q-rows per block (grid-stride): tests the
// dispatch-ramp hypothesis (8704 -> 2560 blocks) and quadruples per-thread
// loads in flight.
// ---------------------------------------------------------------------------
__global__ __launch_bounds__(256) void tail_kernel(
    const float* __restrict__ X,    // oattn
    const float* __restrict__ WT,   // WoT
    float* __restrict__ Y,          // out0
    const ushort* __restrict__ wscr, const float* __restrict__ linv_g,
    float* __restrict__ out1)
{
    __shared__ __align__(16) float xs[16][DD];
    const int t = threadIdx.x;

    if (blockIdx.x < 512) {
        // ---------------- o_proj role ----------------
        const int row0 = blockIdx.x * 16;
        {
            const float4* src = (const float4*)(X + (size_t)row0 * DD);
            float4* dst = (float4*)&xs[0][0];
            for (int i = t; i < 16 * DD / 4; i += 256) dst[i] = src[i];
        }
        __syncthreads();
        if (t < 192) {
            const int jt = (t % 48) * 4;
            const int rowg = t / 48;

            float acc[4][4];
#pragma unroll
            for (int r = 0; r < 4; ++r)
#pragma unroll
                for (int j = 0; j < 4; ++j) acc[r][j] = 0.f;

#pragma unroll 4
            for (int k4 = 0; k4 < DD / 4; ++k4) {
                float4 w0 = *(const float4*)&WT[(size_t)(k4 * 4 + 0) * DD + jt];
                float4 w1 = *(const float4*)&WT[(size_t)(k4 * 4 + 1) * DD + jt];
                float4 w2 = *(const float4*)&WT[(size_t)(k4 * 4 + 2) * DD + jt];
                float4 w3 = *(const float4*)&WT[(size_t)(k4 * 4 + 3) * DD + jt];
#pragma unroll
                for (int r = 0; r < 4; ++r) {
                    float4 xv = *(const float4*)&xs[rowg * 4 + r][k4 * 4];
                    acc[r][0] = fmaf(xv.x, w0.x, acc[r][0]); acc[r][1] = fmaf(xv.x, w0.y, acc[r][1]);
                    acc[r][2] = fmaf(xv.x, w0.z, acc[r][2]); acc[r][3] = fmaf(xv.x, w0.w, acc[r][3]);
                    acc[r][0] = fmaf(xv.y, w1.x, acc[r][0]); acc[r][1] = fmaf(xv.y, w1.y, acc[r][1]);
                    acc[r][2] = fmaf(xv.y, w1.z, acc[r][2]); acc[r][3] = fmaf(xv.y, w1.w, acc[r][3]);
                    acc[r][0] = fmaf(xv.z, w2.x, acc[r][0]); acc[r][1] = fmaf(xv.z, w2.y, acc[r][1]);
                    acc[r][2] = fmaf(xv.z, w2.z, acc[r][2]); acc[r][3] = fmaf(xv.z, w2.w, acc[r][3]);
                    acc[r][0] = fmaf(xv.w, w3.x, acc[r][0]); acc[r][1] = fmaf(xv.w, w3.y, acc[r][1]);
                    acc[r][2] = fmaf(xv.w, w3.z, acc[r][2]); acc[r][3] = fmaf(xv.w, w3.w, acc[r][3]);
                }
            }

#pragma unroll
            for (int r = 0; r < 4; ++r)
                *(float4*)&Y[(size_t)(row0 + rowg * 4 + r) * DD + jt] =
                    make_float4(acc[r][0], acc[r][1], acc[r][2], acc[r][3]);
        }
    } else {
        // ---------------- out1 role: 4 q-rows per block ----------------
        const int bq0 = (blockIdx.x - 512) * 4;
#pragma unroll
        for (int i = 0; i < 4; ++i) {
            const int bq = bq0 + i;
            const int b = bq >> 11;
            const int q = bq & (SS - 1);
            const ushort* base = wscr + (size_t)bq * (HH * SS) + t * 8;

            float li[HH];
#pragma unroll
            for (int hh = 0; hh < HH; ++hh)
                li[hh] = linv_g[((size_t)b * HH + hh) * SS + q] * 0.25f;

            float acc[8];
#pragma unroll
            for (int j = 0; j < 8; ++j) acc[j] = 0.f;

#pragma unroll
            for (int hh = 0; hh < HH; ++hh) {
                short8 wv = *(const short8*)(base + (size_t)hh * SS);
#pragma unroll
                for (int j = 0; j < 8; ++j)
                    acc[j] = fmaf(bf2f((ushort)wv[j]), li[hh], acc[j]);
            }

            float* dst = out1 + (size_t)bq * SS + t * 8;
            *(float4*)dst = make_float4(acc[0], acc[1], acc[2], acc[3]);
            *(float4*)(dst + 4) = make_float4(acc[4], acc[5], acc[6], acc[7]);
        }
    }
}

// ---------------------------------------------------------------------------
extern "C" void kernel_launch(void* const* d_in, const int* in_sizes, int n_in,
                              void* d_out, int out_size, void* d_ws, size_t ws_size,
                              hipStream_t stream)
{
    const float* query = (const float*)d_in[0];
    const float* key   = (const float*)d_in[1];
    const float* value = (const float*)d_in[2];
    const int*   amask = (const int*)d_in[3];
    const float* bias  = (const float*)d_in[4];
    const float* Wq    = (const float*)d_in[5];
    const float* Wk    = (const float*)d_in[6];
    const float* Wv    = (const float*)d_in[7];
    const float* Wo    = (const float*)d_in[8];

    const size_t n_rows = (size_t)BB * SS;
    float* out0 = (float*)d_out;
    float* out1 = out0 + n_rows * DD;

    ushort* qpad  = (ushort*)d_ws;                          // 4 MB
    ushort* kpad  = qpad + n_rows * HH * 64;                // 4 MB
    ushort* vT    = kpad + n_rows * HH * 64;                // 3 MB
    float*  oattn = (float*)(vT + (size_t)BB * HH * 48 * SS);   // 6.3 MB
    float*  WTall = oattn + n_rows * DD;                    // 0.59 MB
    float*  linvg = WTall + 4 * DD * DD;                    // 128 KB
    ushort* wscr  = (ushort*)(linvg + (size_t)BB * HH * SS); // 128 MB

    wt_kernel<<<dim3(6, 6, 4), 256, 0, stream>>>(Wq, Wk, Wv, Wo, WTall);

    qkv_proj_kernel<<<dim3(n_rows / 16, 3), 192, 0, stream>>>(
        query, key, value, WTall, qpad, kpad, vT);

    attn_kernel<<<dim3(BB * SS / QT), 512, 0, stream>>>(
        qpad, kpad, vT, amask, bias, wscr, linvg, oattn);

    tail_kernel<<<dim3(512 + BB * SS / 4), 256, 0, stream>>>(
        oattn, WTall + 3 * DD * DD, out0, wscr, linvg, out1);
}

// Round 12
// 347.910 us; speedup vs baseline: 1.1629x; 1.1629x over previous
//
#include <hip/hip_runtime.h>

#define BB 4
#define SS 2048
#define HH 4
#define DD 192
#define QT 16
#define NT (SS / 2 / 64)
#define NEG_BIG (-1e9f)
#define MB_NEG 0xCE6Eu   // bf16(-1e9) approx

typedef __attribute__((ext_vector_type(8))) short short8;
typedef __attribute__((ext_vector_type(4))) float f32x4;

__device__ inline ushort f2bf(float x) {
    union { float f; unsigned u; } v; v.f = x;
    unsigned r = (v.u + 0x7FFFu + ((v.u >> 16) & 1u)) >> 16;
    return (ushort)r;
}
__device__ inline float bf2f(ushort x) {
    union { unsigned u; float f; } v; v.u = ((unsigned)x) << 16;
    return v.f;
}
// wave-local fence: all prior ds ops complete/visible within this wave
__device__ inline void wave_lds_fence() {
    __builtin_amdgcn_wave_barrier();
    __builtin_amdgcn_s_waitcnt(0xC07F);   // vmcnt(63) expcnt(7) lgkmcnt(0)
    __builtin_amdgcn_wave_barrier();
}

// ---------------------------------------------------------------------------
// Transpose the four weight matrices: WT[c][j] = W[j][c].  grid (6,6,4).
// ---------------------------------------------------------------------------
__global__ __launch_bounds__(256) void wt_kernel(
    const float* __restrict__ Wq, const float* __restrict__ Wk,
    const float* __restrict__ Wv, const float* __restrict__ Wo,
    float* __restrict__ WTall)
{
    __shared__ float tile[32][33];
    const float* W = (blockIdx.z == 0) ? Wq : (blockIdx.z == 1) ? Wk
                   : (blockIdx.z == 2) ? Wv : Wo;
    float* WT = WTall + (size_t)blockIdx.z * DD * DD;
    const int c0 = blockIdx.x * 32, j0 = blockIdx.y * 32;
    const int tx = threadIdx.x & 31, ty = threadIdx.x >> 5;
#pragma unroll
    for (int k = 0; k < 4; ++k)
        tile[ty + 8 * k][tx] = W[(size_t)(j0 + ty + 8 * k) * DD + c0 + tx];
    __syncthreads();
#pragma unroll
    for (int k = 0; k < 4; ++k)
        WT[(size_t)(c0 + ty + 8 * k) * DD + j0 + tx] = tile[tx][ty + 8 * k];
}

// ---------------------------------------------------------------------------
// Fused QKV projection via WT (coalesced). 192 thr, 16 rows/block, grid(512,3).
// Q -> qpad (row-major padded, attn loads it once per wave).
// K -> kpadT in MFMA-FRAGMENT order: per (b,h,kg=key/16): lane l holds
//      (key=l&15, dims (l>>4)*8..+7); frag0 = dims 0..31 (1024B), frag1 =
//      dims 32..63 (+pad).  attn K loads become base + lane*16B (coalesced).
// V -> vTf in fragment order: per (b,h,kb64=key/64,nb): half=(key&63)>>5,
//      lane l = ((key&31)>>3)*16 + (dim&15), byte = key&7.
// ---------------------------------------------------------------------------
__global__ __launch_bounds__(192) void qkv_proj_kernel(
    const float* __restrict__ Xq, const float* __restrict__ Xk,
    const float* __restrict__ Xv, const float* __restrict__ WTall,
    ushort* __restrict__ qpad, ushort* __restrict__ kpadT,
    ushort* __restrict__ vTf)
{
    const int mode = blockIdx.y;
    const float* __restrict__ X = (mode == 0) ? Xq : (mode == 1) ? Xk : Xv;
    const float* __restrict__ WT = WTall + (size_t)mode * DD * DD;

    __shared__ __align__(16) float xs[16][DD];   // 12 KB
    const int row0 = blockIdx.x * 16;
    const int t = threadIdx.x;
    {
        const float4* src = (const float4*)(X + (size_t)row0 * DD);
        float4* dst = (float4*)&xs[0][0];
        for (int i = t; i < 16 * DD / 4; i += 192) dst[i] = src[i];
    }
    __syncthreads();

    const int jt = (t % 48) * 4;
    const int rowg = t / 48;           // 0..3, rows rowg*4 .. rowg*4+3

    float acc[4][4];
#pragma unroll
    for (int r = 0; r < 4; ++r)
#pragma unroll
        for (int j = 0; j < 4; ++j) acc[r][j] = 0.f;

#pragma unroll 2
    for (int k4 = 0; k4 < DD / 4; ++k4) {
        float4 w0 = *(const float4*)&WT[(size_t)(k4 * 4 + 0) * DD + jt];
        float4 w1 = *(const float4*)&WT[(size_t)(k4 * 4 + 1) * DD + jt];
        float4 w2 = *(const float4*)&WT[(size_t)(k4 * 4 + 2) * DD + jt];
        float4 w3 = *(const float4*)&WT[(size_t)(k4 * 4 + 3) * DD + jt];
#pragma unroll
        for (int r = 0; r < 4; ++r) {
            float4 xv = *(const float4*)&xs[rowg * 4 + r][k4 * 4];
            acc[r][0] = fmaf(xv.x, w0.x, acc[r][0]); acc[r][1] = fmaf(xv.x, w0.y, acc[r][1]);
            acc[r][2] = fmaf(xv.x, w0.z, acc[r][2]); acc[r][3] = fmaf(xv.x, w0.w, acc[r][3]);
            acc[r][0] = fmaf(xv.y, w1.x, acc[r][0]); acc[r][1] = fmaf(xv.y, w1.y, acc[r][1]);
            acc[r][2] = fmaf(xv.y, w1.z, acc[r][2]); acc[r][3] = fmaf(xv.y, w1.w, acc[r][3]);
            acc[r][0] = fmaf(xv.z, w2.x, acc[r][0]); acc[r][1] = fmaf(xv.z, w2.y, acc[r][1]);
            acc[r][2] = fmaf(xv.z, w2.z, acc[r][2]); acc[r][3] = fmaf(xv.z, w2.w, acc[r][3]);
            acc[r][0] = fmaf(xv.w, w3.x, acc[r][0]); acc[r][1] = fmaf(xv.w, w3.y, acc[r][1]);
            acc[r][2] = fmaf(xv.w, w3.z, acc[r][2]); acc[r][3] = fmaf(xv.w, w3.w, acc[r][3]);
        }
    }

    const int b = row0 >> 11, s_base = row0 & (SS - 1);

    if (mode == 0) {
        // ---------------- Q: row-major padded ----------------
        const int hd = jt / 48, f = jt % 48;
#pragma unroll
        for (int r = 0; r < 4; ++r) {
            ushort4 o;
            o.x = f2bf(acc[r][0]); o.y = f2bf(acc[r][1]);
            o.z = f2bf(acc[r][2]); o.w = f2bf(acc[r][3]);
            *(ushort4*)&qpad[((size_t)(row0 + rowg * 4 + r) * HH + hd) * 64 + f] = o;
        }
        const int4 z = make_int4(0, 0, 0, 0);
        for (int i = t; i < 128; i += 192) {
            const int row = i >> 3, hh = (i >> 1) & 3, half = i & 1;
            *(int4*)&qpad[((size_t)(row0 + row) * HH + hh) * 64 + 48 + half * 8] = z;
        }
    } else if (mode == 1) {
        // ---------------- K: fragment order ----------------
        const int hd = jt / 48, f0 = jt % 48;
        const int off_base = (f0 < 32)
            ? ((f0 >> 3) * 16) * 8 + (f0 & 7)
            : 512 + (((f0 - 32) >> 3) * 16) * 8 + (f0 & 7);
#pragma unroll
        for (int r = 0; r < 4; ++r) {
            const int s = s_base + rowg * 4 + r;
            ushort4 o;
            o.x = f2bf(acc[r][0]); o.y = f2bf(acc[r][1]);
            o.z = f2bf(acc[r][2]); o.w = f2bf(acc[r][3]);
            const size_t base = ((size_t)(b * HH + hd) * (SS / 16) + (s >> 4)) * 1024;
            *(ushort4*)&kpadT[base + off_base + (size_t)(s & 15) * 8] = o;
        }
        // pad dims 48..63 -> frag1 lane-groups 2,3
        const int4 z = make_int4(0, 0, 0, 0);
        for (int i = t; i < 128; i += 192) {
            const int row = i >> 3, hh = (i >> 1) & 3, half = i & 1;
            const int s = s_base + row;
            const size_t base = ((size_t)(b * HH + hh) * (SS / 16) + (s >> 4)) * 1024;
            *(int4*)&kpadT[base + 512 + ((size_t)((2 + half) * 16 + (s & 15))) * 8] = z;
        }
    } else {
        // ---------------- V: fragment order ----------------
#pragma unroll
        for (int j = 0; j < 4; ++j) {
            const int col = jt + j, hd = col / 48, f = col % 48;
            const int nb = f >> 4, dfrac = f & 15;
#pragma unroll
            for (int p = 0; p < 2; ++p) {
                const int s = s_base + rowg * 4 + 2 * p;
                unsigned pk = (unsigned)f2bf(acc[2 * p][j]) |
                              ((unsigned)f2bf(acc[2 * p + 1][j]) << 16);
                const size_t base =
                    (((size_t)(b * HH + hd) * (SS / 64) + (s >> 6)) * 3 + nb) * 1024;
                const int off = ((s & 63) >> 5) * 512 +
                                (((s & 31) >> 3) * 16 + dfrac) * 8 + (s & 7);
                *(unsigned*)&vTf[base + off] = pk;
            }
        }
    }
}

// ---------------------------------------------------------------------------
// MFMA attention, SINGLE PASS (R9/R10 core), fragment-order K/V loads:
// every inner-loop global load is base + lane*16B (fully coalesced 1KB).
// ---------------------------------------------------------------------------
__global__ __launch_bounds__(512, 4) void attn_kernel(
    const ushort* __restrict__ qpad, const ushort* __restrict__ kpadT,
    const ushort* __restrict__ vTf, const int* __restrict__ mask,
    const float* __restrict__ bias,
    ushort* __restrict__ wscr, float* __restrict__ linv_g,
    float* __restrict__ oattn)
{
    __shared__ __align__(16) ushort wb[2][8][QT][72];  // 36864 B double-buffered
    __shared__ float l_scr[8][QT];                     // 512 B

    const int b  = blockIdx.x >> 7;
    const int q0 = (blockIdx.x & 127) * QT;
    const int t = threadIdx.x;
    const int w = t >> 6;
    const int h = w & 3;
    const int kh = w >> 2;
    const int lane = t & 63;
    const int n16 = lane & 15, quad = lane >> 4;
    const int kbase0 = kh * (SS / 2);

    const ushort* qbase =
        qpad + ((size_t)(b * SS + q0 + n16) * HH + h) * 64 + quad * 8;
    const short8 qa0 = *(const short8*)(qbase);
    const short8 qa1 = *(const short8*)(qbase + 32);

    // fragment-order K/V bases (lane-linear)
    const ushort* kT = kpadT +
        ((size_t)(b * HH + h) * (SS / 16) + (kbase0 >> 4)) * 1024 + (size_t)lane * 8;
    const ushort* vTb = vTf +
        ((size_t)(b * HH + h) * (SS / 64) + (kbase0 >> 6)) * 3 * 1024 + (size_t)lane * 8;

    const int srow = lane >> 4;          // staging row base (+4*rr)
    const int skey = (lane & 15) * 4;    // staging key (float4/int4)
    const int* mrow0 = mask + (size_t)(b * SS + q0) * SS + kbase0 + skey;
    const float* brow0 = bias + (size_t)(h * SS + q0) * SS + kbase0 + skey;

    float l_[4] = {0.f, 0.f, 0.f, 0.f};
    f32x4 pv[3];
#pragma unroll
    for (int nb = 0; nb < 3; ++nb) pv[nb] = (f32x4){0.f, 0.f, 0.f, 0.f};

    // ---- prologue: load kt0, stage into wb[0], load kt1 into regs ----
    int4  mzc[4];
    float4 bvc[4];
#pragma unroll
    for (int rr = 0; rr < 4; ++rr) {
        const int row = rr * 4 + srow;
        mzc[rr] = *(const int4*)(mrow0 + (size_t)row * SS);
        bvc[rr] = *(const float4*)(brow0 + (size_t)row * SS);
    }
#pragma unroll
    for (int rr = 0; rr < 4; ++rr) {
        const int row = rr * 4 + srow;
        ushort4 o;
        o.x = mzc[rr].x ? f2bf(bvc[rr].x) : (ushort)MB_NEG;
        o.y = mzc[rr].y ? f2bf(bvc[rr].y) : (ushort)MB_NEG;
        o.z = mzc[rr].z ? f2bf(bvc[rr].z) : (ushort)MB_NEG;
        o.w = mzc[rr].w ? f2bf(bvc[rr].w) : (ushort)MB_NEG;
        *(ushort4*)&wb[0][w][row][skey] = o;
    }
#pragma unroll
    for (int rr = 0; rr < 4; ++rr) {
        const int row = rr * 4 + srow;
        mzc[rr] = *(const int4*)(mrow0 + (size_t)row * SS + 64);
        bvc[rr] = *(const float4*)(brow0 + (size_t)row * SS + 64);
    }
    wave_lds_fence();   // stage(0) visible

    int buf = 0;
    for (int kt = 0; kt < NT; ++kt) {
        const int kb = kt * 64;

        // ---- QK + exp; w overwrites its own mb slot in wb[buf] ----
#pragma unroll
        for (int g = 0; g < 4; ++g) {
            const ushort* kp = kT + (size_t)(kt * 4 + g) * 1024;
            short8 kf0 = *(const short8*)(kp);
            short8 kf1 = *(const short8*)(kp + 512);
            f32x4 d = {0.f, 0.f, 0.f, 0.f};
            d = __builtin_amdgcn_mfma_f32_16x16x32_bf16(qa0, kf0, d, 0, 0, 0);
            d = __builtin_amdgcn_mfma_f32_16x16x32_bf16(qa1, kf1, d, 0, 0, 0);
#pragma unroll
            for (int r = 0; r < 4; ++r) {
                float wgt = __expf(d[r] + bf2f(wb[buf][w][quad * 4 + r][g * 16 + n16]));
                l_[r] += wgt;
                wb[buf][w][quad * 4 + r][g * 16 + n16] = f2bf(wgt);
            }
        }

        wave_lds_fence();   // FENCE1: w visible; stream(kt-1) reads drained

        // ---- stage kt+1 into wb[buf^1] (drains under PV below) ----
        if (kt + 1 < NT) {
#pragma unroll
            for (int rr = 0; rr < 4; ++rr) {
                const int row = rr * 4 + srow;
                ushort4 o;
                o.x = mzc[rr].x ? f2bf(bvc[rr].x) : (ushort)MB_NEG;
                o.y = mzc[rr].y ? f2bf(bvc[rr].y) : (ushort)MB_NEG;
                o.z = mzc[rr].z ? f2bf(bvc[rr].z) : (ushort)MB_NEG;
                o.w = mzc[rr].w ? f2bf(bvc[rr].w) : (ushort)MB_NEG;
                *(ushort4*)&wb[buf ^ 1][w][row][skey] = o;
            }
        }
        // ---- prefetch kt+2 into regs ----
        if (kt + 2 < NT) {
#pragma unroll
            for (int rr = 0; rr < 4; ++rr) {
                const int row = rr * 4 + srow;
                mzc[rr] = *(const int4*)(mrow0 + (size_t)row * SS + kb + 128);
                bvc[rr] = *(const float4*)(brow0 + (size_t)row * SS + kb + 128);
            }
        }

        // ---- PV with unnormalized w (fragment-order V loads) ----
        const short8 wa0 = *(const short8*)&wb[buf][w][n16][quad * 8];
        const short8 wa1 = *(const short8*)&wb[buf][w][n16][32 + quad * 8];
#pragma unroll
        for (int nb = 0; nb < 3; ++nb) {
            const ushort* vp = vTb + (size_t)(kt * 3 + nb) * 1024;
            short8 v0 = *(const short8*)(vp);
            short8 v1 = *(const short8*)(vp + 512);
            pv[nb] = __builtin_amdgcn_mfma_f32_16x16x32_bf16(wa0, v0, pv[nb], 0, 0, 0);
            pv[nb] = __builtin_amdgcn_mfma_f32_16x16x32_bf16(wa1, v1, pv[nb], 0, 0, 0);
        }

        // ---- stream unnormalized w tile to wscr (b,q,h,k layout) ----
        {
            const int r4 = lane >> 4;
            const int k4 = (lane & 15) * 4;
#pragma unroll
            for (int it = 0; it < 4; ++it) {
                const int row = it * 4 + r4;
                ushort4 wv = *(const ushort4*)&wb[buf][w][row][k4];
                *(ushort4*)&wscr[((size_t)(b * SS + q0 + row) * HH + h) * SS +
                                 kbase0 + kb + k4] = wv;
            }
        }

        wave_lds_fence();   // FENCE2: stage(kt+1) visible before next QK
        buf ^= 1;
    }

    // ---- reduce l across the 16 key-lanes ----
#pragma unroll
    for (int r = 0; r < 4; ++r) {
        float ll = l_[r];
#pragma unroll
        for (int off = 1; off < 16; off <<= 1) ll += __shfl_xor(ll, off);
        l_[r] = ll;
    }
    if (n16 == 0) {
#pragma unroll
        for (int r = 0; r < 4; ++r) l_scr[w][quad * 4 + r] = l_[r];
    }

    // ALL waves must be done with wb before scr (aliasing wb) is written.
    __syncthreads();

    // kh==1 stashes raw pv into LDS scratch (aliases wb)
    float* scr = (float*)&wb[0][0][0][0];
    if (kh == 1) {
#pragma unroll
        for (int nb = 0; nb < 3; ++nb)
            *(f32x4*)&scr[((size_t)(h * 64 + lane)) * 12 + nb * 4] = pv[nb];
    }
    __syncthreads();

    if (kh == 0) {
        float linv[4];
#pragma unroll
        for (int r = 0; r < 4; ++r)
            linv[r] = 1.0f / (l_scr[h][quad * 4 + r] + l_scr[h + 4][quad * 4 + r]);
        if (n16 == 0) {
#pragma unroll
            for (int r = 0; r < 4; ++r)
                linv_g[((size_t)b * HH + h) * SS + q0 + quad * 4 + r] = linv[r];
        }
#pragma unroll
        for (int nb = 0; nb < 3; ++nb) {
            f32x4 po = *(const f32x4*)&scr[((size_t)(h * 64 + lane)) * 12 + nb * 4];
#pragma unroll
            for (int r = 0; r < 4; ++r)
                oattn[((size_t)(b * SS + q0 + quad * 4 + r)) * DD +
                      h * 48 + nb * 16 + n16] = (pv[nb][r] + po[r]) * linv[r];
        }
    }
}

// ---------------------------------------------------------------------------
// Fused tail: o_proj (blocks [0,512)) + out1 (blocks [512, 512+8192)).
// R10 form (1 q-row per out1 block — R11's 4-row variant regressed).
// ---------------------------------------------------------------------------
__global__ __launch_bounds__(256) void tail_kernel(
    const float* __restrict__ X,    // oattn
    const float* __restrict__ WT,   // WoT
    float* __restrict__ Y,          // out0
    const ushort* __restrict__ wscr, const float* __restrict__ linv_g,
    float* __restrict__ out1)
{
    __shared__ __align__(16) float xs[16][DD];
    const int t = threadIdx.x;

    if (blockIdx.x < 512) {
        // ---------------- o_proj role ----------------
        const int row0 = blockIdx.x * 16;
        {
            const float4* src = (const float4*)(X + (size_t)row0 * DD);
            float4* dst = (float4*)&xs[0][0];
            for (int i = t; i < 16 * DD / 4; i += 256) dst[i] = src[i];
        }
        __syncthreads();
        if (t < 192) {
            const int jt = (t % 48) * 4;
            const int rowg = t / 48;

            float acc[4][4];
#pragma unroll
            for (int r = 0; r < 4; ++r)
#pragma unroll
                for (int j = 0; j < 4; ++j) acc[r][j] = 0.f;

#pragma unroll 2
            for (int k4 = 0; k4 < DD / 4; ++k4) {
                float4 w0 = *(const float4*)&WT[(size_t)(k4 * 4 + 0) * DD + jt];
                float4 w1 = *(const float4*)&WT[(size_t)(k4 * 4 + 1) * DD + jt];
                float4 w2 = *(const float4*)&WT[(size_t)(k4 * 4 + 2) * DD + jt];
                float4 w3 = *(const float4*)&WT[(size_t)(k4 * 4 + 3) * DD + jt];
#pragma unroll
                for (int r = 0; r < 4; ++r) {
                    float4 xv = *(const float4*)&xs[rowg * 4 + r][k4 * 4];
                    acc[r][0] = fmaf(xv.x, w0.x, acc[r][0]); acc[r][1] = fmaf(xv.x, w0.y, acc[r][1]);
                    acc[r][2] = fmaf(xv.x, w0.z, acc[r][2]); acc[r][3] = fmaf(xv.x, w0.w, acc[r][3]);
                    acc[r][0] = fmaf(xv.y, w1.x, acc[r][0]); acc[r][1] = fmaf(xv.y, w1.y, acc[r][1]);
                    acc[r][2] = fmaf(xv.y, w1.z, acc[r][2]); acc[r][3] = fmaf(xv.y, w1.w, acc[r][3]);
                    acc[r][0] = fmaf(xv.z, w2.x, acc[r][0]); acc[r][1] = fmaf(xv.z, w2.y, acc[r][1]);
                    acc[r][2] = fmaf(xv.z, w2.z, acc[r][2]); acc[r][3] = fmaf(xv.z, w2.w, acc[r][3]);
                    acc[r][0] = fmaf(xv.w, w3.x, acc[r][0]); acc[r][1] = fmaf(xv.w, w3.y, acc[r][1]);
                    acc[r][2] = fmaf(xv.w, w3.z, acc[r][2]); acc[r][3] = fmaf(xv.w, w3.w, acc[r][3]);
                }
            }

#pragma unroll
            for (int r = 0; r < 4; ++r)
                *(float4*)&Y[(size_t)(row0 + rowg * 4 + r) * DD + jt] =
                    make_float4(acc[r][0], acc[r][1], acc[r][2], acc[r][3]);
        }
    } else {
        // ---------------- out1 role ----------------
        const int bq = blockIdx.x - 512;
        const int b = bq >> 11;
        const int q = bq & (SS - 1);
        const ushort* base = wscr + (size_t)bq * (HH * SS) + t * 8;

        float li[HH];
#pragma unroll
        for (int hh = 0; hh < HH; ++hh)
            li[hh] = linv_g[((size_t)b * HH + hh) * SS + q] * 0.25f;

        float acc[8];
#pragma unroll
        for (int j = 0; j < 8; ++j) acc[j] = 0.f;

#pragma unroll
        for (int hh = 0; hh < HH; ++hh) {
            short8 wv = *(const short8*)(base + (size_t)hh * SS);
#pragma unroll
            for (int j = 0; j < 8; ++j)
                acc[j] = fmaf(bf2f((ushort)wv[j]), li[hh], acc[j]);
        }

        float* dst = out1 + (size_t)bq * SS + t * 8;
        *(float4*)dst = make_float4(acc[0], acc[1], acc[2], acc[3]);
        *(float4*)(dst + 4) = make_float4(acc[4], acc[5], acc[6], acc[7]);
    }
}

// ---------------------------------------------------------------------------
extern "C" void kernel_launch(void* const* d_in, const int* in_sizes, int n_in,
                              void* d_out, int out_size, void* d_ws, size_t ws_size,
                              hipStream_t stream)
{
    const float* query = (const float*)d_in[0];
    const float* key   = (const float*)d_in[1];
    const float* value = (const float*)d_in[2];
    const int*   amask = (const int*)d_in[3];
    const float* bias  = (const float*)d_in[4];
    const float* Wq    = (const float*)d_in[5];
    const float* Wk    = (const float*)d_in[6];
    const float* Wv    = (const float*)d_in[7];
    const float* Wo    = (const float*)d_in[8];

    const size_t n_rows = (size_t)BB * SS;
    float* out0 = (float*)d_out;
    float* out1 = out0 + n_rows * DD;

    ushort* qpad  = (ushort*)d_ws;                          // 4 MB
    ushort* kpadT = qpad + n_rows * HH * 64;                // 4 MB (fragment order)
    ushort* vTf   = kpadT + n_rows * HH * 64;               // 3 MB (fragment order)
    float*  oattn = (float*)(vTf + (size_t)BB * HH * 48 * SS);  // 6.3 MB
    float*  WTall = oattn + n_rows * DD;                    // 0.59 MB
    float*  linvg = WTall + 4 * DD * DD;                    // 128 KB
    ushort* wscr  = (ushort*)(linvg + (size_t)BB * HH * SS); // 128 MB

    wt_kernel<<<dim3(6, 6, 4), 256, 0, stream>>>(Wq, Wk, Wv, Wo, WTall);

    qkv_proj_kernel<<<dim3(n_rows / 16, 3), 192, 0, stream>>>(
        query, key, value, WTall, qpad, kpadT, vTf);

    attn_kernel<<<dim3(BB * SS / QT), 512, 0, stream>>>(
        qpad, kpadT, vTf, amask, bias, wscr, linvg, oattn);

    tail_kernel<<<dim3(512 + BB * SS), 256, 0, stream>>>(
        oattn, WTall + 3 * DD * DD, out0, wscr, linvg, out1);
}